// Round 1
// baseline (14543.974 us; speedup 1.0000x reference)
//
#include <hip/hip_runtime.h>

// Output layout (flat f32, reference return order):
//   xhat  : B*L*N   = 13,107,200  @ 0
//   mu    : B*D     =      4,096  @ 13,107,200
//   logvar: B*D     =      4,096  @ 13,111,296
//   z_traj: B*L*D   =    819,200  @ 13,115,392
//   zdiff : B*(L-1)*D =  815,104  @ 13,934,592
#define OFF_MU   13107200
#define OFF_LV   13111296
#define OFF_ZT   13115392
#define OFF_ZD   13934592

__device__ __forceinline__ float silu_f(float x) {
    return x / (1.0f + __expf(-x));
}

// ---------------------------------------------------------------------------
// Encoder: one block per batch row. x0(256) -> 512 -> 256 -> 128 -> mu/lv(16)
// Writes mu, logvar, and z0 into z_traj[:,0,:].
// ---------------------------------------------------------------------------
__global__ __launch_bounds__(256) void enc_kernel(
    const float* __restrict__ xseq, const float* __restrict__ eps,
    const float* __restrict__ w1, const float* __restrict__ b1,
    const float* __restrict__ w2, const float* __restrict__ b2,
    const float* __restrict__ w3, const float* __restrict__ b3,
    const float* __restrict__ muw, const float* __restrict__ mub,
    const float* __restrict__ lvw, const float* __restrict__ lvb,
    float* __restrict__ out)
{
    __shared__ float xr[256];
    __shared__ float h1[512];
    __shared__ float h2[256];
    __shared__ float h3[128];

    const int t = threadIdx.x;
    const int b = blockIdx.x;

    xr[t] = xseq[b * (200 * 256) + t];   // x_seq[b, 0, :]
    __syncthreads();

    // L1: 512 outputs, K=256 (2 outputs per thread)
    {
        float acc0 = b1[t], acc1 = b1[t + 256];
        for (int i = 0; i < 256; ++i) {
            float xv = xr[i];
            acc0 = fmaf(xv, w1[i * 512 + t],       acc0);
            acc1 = fmaf(xv, w1[i * 512 + t + 256], acc1);
        }
        h1[t]       = fmaxf(acc0, 0.0f);
        h1[t + 256] = fmaxf(acc1, 0.0f);
    }
    __syncthreads();

    // L2: 256 outputs, K=512
    {
        float acc = b2[t];
        for (int i = 0; i < 512; ++i) acc = fmaf(h1[i], w2[i * 256 + t], acc);
        h2[t] = fmaxf(acc, 0.0f);
    }
    __syncthreads();

    // L3: 128 outputs, K=256
    if (t < 128) {
        float acc = b3[t];
        for (int i = 0; i < 256; ++i) acc = fmaf(h2[i], w3[i * 128 + t], acc);
        h3[t] = fmaxf(acc, 0.0f);
    }
    __syncthreads();

    // heads: mu, logvar (16 each, K=128); z0 = mu + exp(0.5*lv)*eps
    if (t < 16) {
        float mu = mub[t], lv = lvb[t];
        for (int i = 0; i < 128; ++i) {
            float hv = h3[i];
            mu = fmaf(hv, muw[i * 16 + t], mu);
            lv = fmaf(hv, lvw[i * 16 + t], lv);
        }
        out[OFF_MU + b * 16 + t] = mu;
        out[OFF_LV + b * 16 + t] = lv;
        float z0 = mu + __expf(0.5f * lv) * eps[b * 16 + t];
        out[OFF_ZT + b * 3200 + t] = z0;   // z_traj[b, 0, :]
    }
}

// ---------------------------------------------------------------------------
// ODE integrator: one block (256 thr = 4 waves) per batch element.
// Persistent loop over 199 intervals x 8 substeps x 6 dopri stages.
// Weights live in registers; activations pass through LDS broadcast reads.
// Thread roles: j = tid&127 (hidden column), c = tid>>7 (K-half).
// z and k1..k6 state live in lanes 0..15's registers.
// ---------------------------------------------------------------------------
__global__ __launch_bounds__(256, 1) void ode_kernel(
    const float* __restrict__ tvec,
    const float* __restrict__ ow1, const float* __restrict__ ob1,
    const float* __restrict__ ow2, const float* __restrict__ ob2,
    const float* __restrict__ ow3, const float* __restrict__ ob3,
    const float* __restrict__ lng, const float* __restrict__ lnb,
    float* __restrict__ out)
{
    __shared__ __align__(16) float zarg[16];
    __shared__ __align__(16) float a1s[128];
    __shared__ __align__(16) float a2s[128];
    __shared__ __align__(16) float part[256];
    __shared__ float p3[16 * 17];   // layer-3 partials, padded stride 17

    const int tid = threadIdx.x;
    const int b   = blockIdx.x;
    const int j   = tid & 127;
    const int c   = tid >> 7;      // K-half for L1/L2
    const int d3  = tid & 15;      // layer-3 output dim
    const int kc  = tid >> 4;      // layer-3 K-chunk (0..15, chunks of 8)

    // register-resident weights
    float w1r[8], w2r[64], w3r[8];
#pragma unroll
    for (int p = 0; p < 8; ++p)  w1r[p] = ow1[(8 * c + p) * 128 + j];
#pragma unroll
    for (int k = 0; k < 64; ++k) w2r[k] = ow2[(64 * c + k) * 128 + j];
#pragma unroll
    for (int p = 0; p < 8; ++p)  w3r[p] = ow3[(8 * kc + p) * 16 + d3];
    const float b1j  = ob1[j];
    const float b2j  = ob2[j];
    const float b3d  = ob3[d3];
    const float lngd = lng[d3];
    const float lnbd = lnb[d3];

    float* ztraj = out + OFF_ZT + b * 3200;   // [200][16]
    float* zdiff = out + OFF_ZD + b * 3184;   // [199][16]

    float z = 0.0f;
    if (tid < 16) z = ztraj[tid];             // z0 from encoder

    float kv[6] = {0.f, 0.f, 0.f, 0.f, 0.f, 0.f};

    // one evaluation of f(zarg); zarg must be in LDS and synced on entry.
    auto feval = [&](float& ret) {
        // L1 partial (K-half of 8)
        const float4* za4 = (const float4*)zarg;
        float4 za0 = za4[2 * c], za1 = za4[2 * c + 1];
        float p1 = za0.x * w1r[0] + za0.y * w1r[1] + za0.z * w1r[2] + za0.w * w1r[3]
                 + za1.x * w1r[4] + za1.y * w1r[5] + za1.z * w1r[6] + za1.w * w1r[7];
        part[c * 128 + j] = p1;
        __syncthreads();
        if (tid < 128) a1s[tid] = silu_f(part[tid] + part[128 + tid] + b1j);
        __syncthreads();

        // L2 partial (K-half of 64); a1 via broadcast float4 reads
        const float4* a14 = (const float4*)(a1s + 64 * c);
        float acc = 0.0f;
#pragma unroll
        for (int q = 0; q < 16; ++q) {
            float4 av = a14[q];
            acc += av.x * w2r[4 * q + 0] + av.y * w2r[4 * q + 1]
                 + av.z * w2r[4 * q + 2] + av.w * w2r[4 * q + 3];
        }
        part[c * 128 + j] = acc;
        __syncthreads();
        if (tid < 128) a2s[tid] = silu_f(part[tid] + part[128 + tid] + b2j);
        __syncthreads();

        // L3: 16 outputs x 16 K-chunks of 8
        const float4* a24 = (const float4*)(a2s + 8 * kc);
        float4 av0 = a24[0], av1 = a24[1];
        float pp = av0.x * w3r[0] + av0.y * w3r[1] + av0.z * w3r[2] + av0.w * w3r[3]
                 + av1.x * w3r[4] + av1.y * w3r[5] + av1.z * w3r[6] + av1.w * w3r[7];
        p3[kc * 17 + d3] = pp;
        __syncthreads();

        // combine + layernorm in lanes 0..15 (wave 0)
        if (tid < 16) {
            float dz = b3d;
#pragma unroll
            for (int q = 0; q < 16; ++q) dz += p3[q * 17 + tid];
            float s = dz;
            s += __shfl_xor(s, 1); s += __shfl_xor(s, 2);
            s += __shfl_xor(s, 4); s += __shfl_xor(s, 8);
            float m  = s * 0.0625f;
            float df = dz - m;
            float ss = df * df;
            ss += __shfl_xor(ss, 1); ss += __shfl_xor(ss, 2);
            ss += __shfl_xor(ss, 4); ss += __shfl_xor(ss, 8);
            float v = ss * 0.0625f;
            ret = df * rsqrtf(v + 1e-5f) * lngd + lnbd;
        }
    };

    auto setz = [&](float v) {
        if (tid < 16) zarg[tid] = v;
        __syncthreads();
    };

    for (int l = 0; l < 199; ++l) {
        const float dt = tvec[l + 1] - tvec[l];
        const float h  = dt * 0.125f;         // dt / K, K=8 (exact)
        const float zstart = z;
        for (int s = 0; s < 8; ++s) {
            setz(z);
            feval(kv[0]);
            setz(z + h * (kv[0] * (float)(1.0 / 5.0)));
            feval(kv[1]);
            setz(z + h * ((float)(3.0 / 40.0) * kv[0] + (float)(9.0 / 40.0) * kv[1]));
            feval(kv[2]);
            setz(z + h * ((float)(44.0 / 45.0) * kv[0] - (float)(56.0 / 15.0) * kv[1]
                        + (float)(32.0 / 9.0) * kv[2]));
            feval(kv[3]);
            setz(z + h * ((float)(19372.0 / 6561.0) * kv[0] - (float)(25360.0 / 2187.0) * kv[1]
                        + (float)(64448.0 / 6561.0) * kv[2] - (float)(212.0 / 729.0) * kv[3]));
            feval(kv[4]);
            setz(z + h * ((float)(9017.0 / 3168.0) * kv[0] - (float)(355.0 / 33.0) * kv[1]
                        + (float)(46732.0 / 5247.0) * kv[2] + (float)(49.0 / 176.0) * kv[3]
                        - (float)(5103.0 / 18656.0) * kv[4]));
            feval(kv[5]);
            z = z + h * ((float)(35.0 / 384.0) * kv[0] + (float)(500.0 / 1113.0) * kv[2]
                       + (float)(125.0 / 192.0) * kv[3] - (float)(2187.0 / 6784.0) * kv[4]
                       + (float)(11.0 / 84.0) * kv[5]);
        }
        if (tid < 16) {
            ztraj[(l + 1) * 16 + tid] = z;
            zdiff[l * 16 + tid] = (z - zstart) / dt;
        }
    }
}

// ---------------------------------------------------------------------------
// Decoder: fused 3-layer MLP over 51200 rows. M-tile=16, 256 threads,
// thread micro-tile 2 rows x 16 cols. g1/g2 share one LDS buffer (~34 KB).
// ---------------------------------------------------------------------------
#define GS 516   // padded LDS stride for the 16x512 activation tile

__global__ __launch_bounds__(256, 2) void dec_kernel(
    const float* __restrict__ ztr,
    const float* __restrict__ w1, const float* __restrict__ b1,
    const float* __restrict__ w2, const float* __restrict__ b2,
    const float* __restrict__ w3, const float* __restrict__ b3,
    float* __restrict__ xhat)
{
    __shared__ __align__(16) float zt[16 * 17];
    __shared__ __align__(16) float g[16 * GS];

    const int t    = threadIdx.x;
    const int blk  = blockIdx.x;
    const int tr   = t >> 5;         // 0..7
    const int tc   = t & 31;         // 0..31
    const int row0 = blk * 16;
    const int r0   = 2 * tr;

    {
        int r = t >> 4, d = t & 15;
        zt[r * 17 + d] = ztr[(row0 + r) * 16 + d];
    }
    __syncthreads();

    // Phase A: g1 = relu(z @ w1 + b1), K=16
    {
        float acc[2][16];
#pragma unroll
        for (int p = 0; p < 2; ++p)
#pragma unroll
            for (int i = 0; i < 16; ++i) acc[p][i] = 0.0f;

#pragma unroll
        for (int k = 0; k < 16; ++k) {
            float a0 = zt[(r0 + 0) * 17 + k];
            float a1 = zt[(r0 + 1) * 17 + k];
            const float4* wr = (const float4*)(w1 + k * 512 + 16 * tc);
#pragma unroll
            for (int u = 0; u < 4; ++u) {
                float4 wv = wr[u];
                acc[0][4 * u + 0] = fmaf(a0, wv.x, acc[0][4 * u + 0]);
                acc[0][4 * u + 1] = fmaf(a0, wv.y, acc[0][4 * u + 1]);
                acc[0][4 * u + 2] = fmaf(a0, wv.z, acc[0][4 * u + 2]);
                acc[0][4 * u + 3] = fmaf(a0, wv.w, acc[0][4 * u + 3]);
                acc[1][4 * u + 0] = fmaf(a1, wv.x, acc[1][4 * u + 0]);
                acc[1][4 * u + 1] = fmaf(a1, wv.y, acc[1][4 * u + 1]);
                acc[1][4 * u + 2] = fmaf(a1, wv.z, acc[1][4 * u + 2]);
                acc[1][4 * u + 3] = fmaf(a1, wv.w, acc[1][4 * u + 3]);
            }
        }
        const float4* bb = (const float4*)(b1 + 16 * tc);
#pragma unroll
        for (int u = 0; u < 4; ++u) {
            float4 bv = bb[u];
#pragma unroll
            for (int p = 0; p < 2; ++p) {
                g[(r0 + p) * GS + 16 * tc + 4 * u + 0] = fmaxf(acc[p][4 * u + 0] + bv.x, 0.0f);
                g[(r0 + p) * GS + 16 * tc + 4 * u + 1] = fmaxf(acc[p][4 * u + 1] + bv.y, 0.0f);
                g[(r0 + p) * GS + 16 * tc + 4 * u + 2] = fmaxf(acc[p][4 * u + 2] + bv.z, 0.0f);
                g[(r0 + p) * GS + 16 * tc + 4 * u + 3] = fmaxf(acc[p][4 * u + 3] + bv.w, 0.0f);
            }
        }
    }
    __syncthreads();

    // Phase B: g2 = relu(g1 @ w2 + b2), K=512
    {
        float accB[2][16];
#pragma unroll
        for (int p = 0; p < 2; ++p)
#pragma unroll
            for (int i = 0; i < 16; ++i) accB[p][i] = 0.0f;

        for (int k4 = 0; k4 < 128; ++k4) {
            float4 av0 = *(const float4*)&g[(r0 + 0) * GS + 4 * k4];
            float4 av1 = *(const float4*)&g[(r0 + 1) * GS + 4 * k4];
            float a0[4] = {av0.x, av0.y, av0.z, av0.w};
            float a1[4] = {av1.x, av1.y, av1.z, av1.w};
#pragma unroll
            for (int u = 0; u < 4; ++u) {
                const float4* wr = (const float4*)(w2 + (4 * k4 + u) * 512 + 16 * tc);
#pragma unroll
                for (int q = 0; q < 4; ++q) {
                    float4 wv = wr[q];
                    accB[0][4 * q + 0] = fmaf(a0[u], wv.x, accB[0][4 * q + 0]);
                    accB[0][4 * q + 1] = fmaf(a0[u], wv.y, accB[0][4 * q + 1]);
                    accB[0][4 * q + 2] = fmaf(a0[u], wv.z, accB[0][4 * q + 2]);
                    accB[0][4 * q + 3] = fmaf(a0[u], wv.w, accB[0][4 * q + 3]);
                    accB[1][4 * q + 0] = fmaf(a1[u], wv.x, accB[1][4 * q + 0]);
                    accB[1][4 * q + 1] = fmaf(a1[u], wv.y, accB[1][4 * q + 1]);
                    accB[1][4 * q + 2] = fmaf(a1[u], wv.z, accB[1][4 * q + 2]);
                    accB[1][4 * q + 3] = fmaf(a1[u], wv.w, accB[1][4 * q + 3]);
                }
            }
        }
        __syncthreads();   // everyone done reading g1
        const float4* bb = (const float4*)(b2 + 16 * tc);
#pragma unroll
        for (int u = 0; u < 4; ++u) {
            float4 bv = bb[u];
#pragma unroll
            for (int p = 0; p < 2; ++p) {
                g[(r0 + p) * GS + 16 * tc + 4 * u + 0] = fmaxf(accB[p][4 * u + 0] + bv.x, 0.0f);
                g[(r0 + p) * GS + 16 * tc + 4 * u + 1] = fmaxf(accB[p][4 * u + 1] + bv.y, 0.0f);
                g[(r0 + p) * GS + 16 * tc + 4 * u + 2] = fmaxf(accB[p][4 * u + 2] + bv.z, 0.0f);
                g[(r0 + p) * GS + 16 * tc + 4 * u + 3] = fmaxf(accB[p][4 * u + 3] + bv.w, 0.0f);
            }
        }
    }
    __syncthreads();

    // Phase C: xhat = g2 @ w3 + b3, N=256 (8 cols/thread), K=512
    {
        float accC[2][8];
#pragma unroll
        for (int p = 0; p < 2; ++p)
#pragma unroll
            for (int i = 0; i < 8; ++i) accC[p][i] = 0.0f;

        for (int k4 = 0; k4 < 128; ++k4) {
            float4 av0 = *(const float4*)&g[(r0 + 0) * GS + 4 * k4];
            float4 av1 = *(const float4*)&g[(r0 + 1) * GS + 4 * k4];
            float a0[4] = {av0.x, av0.y, av0.z, av0.w};
            float a1[4] = {av1.x, av1.y, av1.z, av1.w};
#pragma unroll
            for (int u = 0; u < 4; ++u) {
                const float4* wr = (const float4*)(w3 + (4 * k4 + u) * 256 + 8 * tc);
                float4 w0 = wr[0], w1v = wr[1];
                accC[0][0] = fmaf(a0[u], w0.x,  accC[0][0]);
                accC[0][1] = fmaf(a0[u], w0.y,  accC[0][1]);
                accC[0][2] = fmaf(a0[u], w0.z,  accC[0][2]);
                accC[0][3] = fmaf(a0[u], w0.w,  accC[0][3]);
                accC[0][4] = fmaf(a0[u], w1v.x, accC[0][4]);
                accC[0][5] = fmaf(a0[u], w1v.y, accC[0][5]);
                accC[0][6] = fmaf(a0[u], w1v.z, accC[0][6]);
                accC[0][7] = fmaf(a0[u], w1v.w, accC[0][7]);
                accC[1][0] = fmaf(a1[u], w0.x,  accC[1][0]);
                accC[1][1] = fmaf(a1[u], w0.y,  accC[1][1]);
                accC[1][2] = fmaf(a1[u], w0.z,  accC[1][2]);
                accC[1][3] = fmaf(a1[u], w0.w,  accC[1][3]);
                accC[1][4] = fmaf(a1[u], w1v.x, accC[1][4]);
                accC[1][5] = fmaf(a1[u], w1v.y, accC[1][5]);
                accC[1][6] = fmaf(a1[u], w1v.z, accC[1][6]);
                accC[1][7] = fmaf(a1[u], w1v.w, accC[1][7]);
            }
        }
        const float4* bb = (const float4*)(b3 + 8 * tc);
        float4 bv0 = bb[0], bv1 = bb[1];
#pragma unroll
        for (int p = 0; p < 2; ++p) {
            float4 o0 = make_float4(accC[p][0] + bv0.x, accC[p][1] + bv0.y,
                                    accC[p][2] + bv0.z, accC[p][3] + bv0.w);
            float4 o1 = make_float4(accC[p][4] + bv1.x, accC[p][5] + bv1.y,
                                    accC[p][6] + bv1.z, accC[p][7] + bv1.w);
            float* dst = xhat + (size_t)(row0 + r0 + p) * 256 + 8 * tc;
            *(float4*)(dst)     = o0;
            *(float4*)(dst + 4) = o1;
        }
    }
}

extern "C" void kernel_launch(void* const* d_in, const int* in_sizes, int n_in,
                              void* d_out, int out_size, void* d_ws, size_t ws_size,
                              hipStream_t stream) {
    const float* x_seq  = (const float*)d_in[0];
    const float* tvec   = (const float*)d_in[1];
    const float* eps    = (const float*)d_in[2];
    const float* enc_w1 = (const float*)d_in[3];
    const float* enc_b1 = (const float*)d_in[4];
    const float* enc_w2 = (const float*)d_in[5];
    const float* enc_b2 = (const float*)d_in[6];
    const float* enc_w3 = (const float*)d_in[7];
    const float* enc_b3 = (const float*)d_in[8];
    const float* mu_w   = (const float*)d_in[9];
    const float* mu_b   = (const float*)d_in[10];
    const float* lv_w   = (const float*)d_in[11];
    const float* lv_b   = (const float*)d_in[12];
    const float* ode_w1 = (const float*)d_in[13];
    const float* ode_b1 = (const float*)d_in[14];
    const float* ode_w2 = (const float*)d_in[15];
    const float* ode_b2 = (const float*)d_in[16];
    const float* ode_w3 = (const float*)d_in[17];
    const float* ode_b3 = (const float*)d_in[18];
    const float* ln_g   = (const float*)d_in[19];
    const float* ln_b   = (const float*)d_in[20];
    const float* dec_w1 = (const float*)d_in[21];
    const float* dec_b1 = (const float*)d_in[22];
    const float* dec_w2 = (const float*)d_in[23];
    const float* dec_b2 = (const float*)d_in[24];
    const float* dec_w3 = (const float*)d_in[25];
    const float* dec_b3 = (const float*)d_in[26];
    float* out = (float*)d_out;

    enc_kernel<<<256, 256, 0, stream>>>(x_seq, eps, enc_w1, enc_b1, enc_w2, enc_b2,
                                        enc_w3, enc_b3, mu_w, mu_b, lv_w, lv_b, out);
    ode_kernel<<<256, 256, 0, stream>>>(tvec, ode_w1, ode_b1, ode_w2, ode_b2,
                                        ode_w3, ode_b3, ln_g, ln_b, out);
    dec_kernel<<<3200, 256, 0, stream>>>(out + OFF_ZT, dec_w1, dec_b1, dec_w2, dec_b2,
                                         dec_w3, dec_b3, out);
}